// Round 4
// baseline (224.387 us; speedup 1.0000x reference)
//
#include <hip/hip_runtime.h>

#define SZ   256   // image size
#define NPTS 128   // points per batch
#define NB3  6     // bs * ncam = 2*3

// v_exp_f32 / v_log_f32: base-2 exp and log, single-instruction on gfx950.
#define EXP2F(x) __builtin_amdgcn_exp2f(x)
#define LOG2F(x) __builtin_amdgcn_logf(x)

#define MASK_BLOCKS  (NB3 * SZ)            // 1536: one row of masks per block
#define ROWS_PER_BLK 16
#define BLOB_BLOCKS  (NB3 * NPTS * (SZ / ROWS_PER_BLK))  // 12288

// Global normalization over all 6 camera values (jnp .mean()/.max() reduce the
// whole (2,3) array, not per-row).
__device__ __forceinline__ float norm6(const float* __restrict__ v, int idx) {
    float a0 = v[0], a1 = v[1], a2 = v[2], a3 = v[3], a4 = v[4], a5 = v[5];
    float mean = (a0 + a1 + a2 + a3 + a4 + a5) * (1.0f / 6.0f);
    float inv = 1.0f / mean;
    float b0 = a0 * inv, b1 = a1 * inv, b2 = a2 * inv;
    float b3 = a3 * inv, b4 = a4 * inv, b5 = a5 * inv;
    float d = fmaxf(fmaxf(fmaxf(fabsf(b0 - 1.f), fabsf(b1 - 1.f)),
                          fmaxf(fabsf(b2 - 1.f), fabsf(b3 - 1.f))),
                    fmaxf(fabsf(b4 - 1.f), fabsf(b5 - 1.f)));
    float sf = 0.2f / d;                 // d==0 -> inf -> takes 'vi' branch
    float vi = v[idx] * inv;
    return (sf < 1.0f) ? (vi - 1.0f) * sf + 1.0f : vi;
}

// blob = exp(-(dst*q)^e) = exp2(-exp2(e*log2(dst) + c2)),
//   c2 = e*log2(q) + log2(log2(e))
__global__ __launch_bounds__(256) void render_kernel(
    const float* __restrict__ points,       // (2,3,128,2)
    const float* __restrict__ sigmas,       // (2,128)
    const float* __restrict__ exponents,    // (2,128)
    const float* __restrict__ intensities,  // (2,128)
    const float* __restrict__ cam_s,        // (2,3)
    const float* __restrict__ cam_e,        // (2,3)
    const float* __restrict__ cam_i,        // (2,3)
    float* __restrict__ masks,              // (6,256,256)
    float* __restrict__ blobs)              // (6,128,256,256)
{
    const int bid = blockIdx.x;
    const int tid = threadIdx.x;
    const float C = 0.5287663729448977f;    // log2(log2(e))

    if (bid < MASK_BLOCKS) {
        // ---- mask path: one mask row per block, 1 px/thread, loop over n ----
        __shared__ float4 s_p[NPTS];   // px, py, e, c2
        __shared__ float  s_i[NPTS];   // intensity
        const int b3 = bid >> 8;       // [0,6)
        const int y  = bid & 255;

        if (tid < NPTS) {
            const int b = b3 / 3;
            const float cs = norm6(cam_s, b3);
            const float ce = norm6(cam_e, b3);
            const float ci = norm6(cam_i, b3);
            float px = points[(b3 * NPTS + tid) * 2 + 0];
            float py = points[(b3 * NPTS + tid) * 2 + 1];
            px = fminf(fmaxf((px - 128.0f) * (1.0f / 128.0f), -1.0f), 1.0f);
            py = fminf(fmaxf((py - 128.0f) * (1.0f / 128.0f), -1.0f), 1.0f);
            const float sg = sigmas[b * NPTS + tid] * cs;
            const float e  = exponents[b * NPTS + tid] * ce;
            const float q  = 1.0f / (2.0f * sg * sg);
            s_p[tid] = make_float4(px, py, e, fmaf(e, LOG2F(q), C));
            s_i[tid] = intensities[b * NPTS + tid] * ci;
        }
        __syncthreads();

        const float gy = -1.0f + (float)y   * (2.0f / 255.0f);
        const float gx = -1.0f + (float)tid * (2.0f / 255.0f);

        float m = 0.0f;
        #pragma unroll 4
        for (int n = 0; n < NPTS; ++n) {
            const float4 p = s_p[n];
            const float dx = gx - p.x;
            const float dy = gy - p.y;
            const float u  = fmaf(dx, dx, dy * dy);
            const float t  = EXP2F(fmaf(p.z, LOG2F(u), p.w));
            const float bl = EXP2F(-t);              // u==0 -> t=0 -> bl=1
            m = fmaxf(m, bl * s_i[n]);
        }
        masks[(size_t)b3 * SZ * SZ + (size_t)y * SZ + tid] = fminf(m, 1.0f);
    } else {
        // ---- blob path: 16 consecutive rows of ONE (b3,n) plane per block ----
        const int pid   = bid - MASK_BLOCKS;
        const int plane = pid >> 4;                  // b3*128 + n
        const int r0    = (pid & 15) * ROWS_PER_BLK;
        const int b3    = plane >> 7;
        const int n     = plane & 127;
        const int b     = b3 / 3;

        // block-uniform point params -> scalar registers
        const float cs = norm6(cam_s, b3);
        const float ce = norm6(cam_e, b3);
        float px = points[(b3 * NPTS + n) * 2 + 0];
        float py = points[(b3 * NPTS + n) * 2 + 1];
        px = fminf(fmaxf((px - 128.0f) * (1.0f / 128.0f), -1.0f), 1.0f);
        py = fminf(fmaxf((py - 128.0f) * (1.0f / 128.0f), -1.0f), 1.0f);
        const float sg = sigmas[b * NPTS + n] * cs;
        const float e  = exponents[b * NPTS + n] * ce;
        const float q  = 1.0f / (2.0f * sg * sg);
        const float c2 = fmaf(e, LOG2F(q), C);

        const int wave = tid >> 6;                   // 4 waves: 4 rows each
        const int x0   = (tid & 63) << 2;            // 4 px per lane -> 1 row/wave
        const float gx0 = -1.0f + (float)(x0    ) * (2.0f / 255.0f);
        const float gx1 = -1.0f + (float)(x0 + 1) * (2.0f / 255.0f);
        const float gx2 = -1.0f + (float)(x0 + 2) * (2.0f / 255.0f);
        const float gx3 = -1.0f + (float)(x0 + 3) * (2.0f / 255.0f);
        const float d0 = gx0 - px, d1 = gx1 - px, d2 = gx2 - px, d3 = gx3 - px;
        const float dx20 = d0 * d0, dx21 = d1 * d1;
        const float dx22 = d2 * d2, dx23 = d3 * d3;

        const int row0 = r0 + wave * 4;
        float* base = blobs + (size_t)plane * (SZ * SZ) + (size_t)row0 * SZ + x0;

        #pragma unroll
        for (int i = 0; i < 4; ++i) {                // 4 consecutive rows/wave
            const float gy  = -1.0f + (float)(row0 + i) * (2.0f / 255.0f);
            const float dy  = gy - py;
            const float dy2 = dy * dy;
            const float u0 = dx20 + dy2, u1 = dx21 + dy2;
            const float u2 = dx22 + dy2, u3 = dx23 + dy2;
            const float bl0 = EXP2F(-EXP2F(fmaf(e, LOG2F(u0), c2)));
            const float bl1 = EXP2F(-EXP2F(fmaf(e, LOG2F(u1), c2)));
            const float bl2 = EXP2F(-EXP2F(fmaf(e, LOG2F(u2), c2)));
            const float bl3 = EXP2F(-EXP2F(fmaf(e, LOG2F(u3), c2)));
            *((float4*)(base + (size_t)i * SZ)) = make_float4(bl0, bl1, bl2, bl3);
        }
    }
}

extern "C" void kernel_launch(void* const* d_in, const int* in_sizes, int n_in,
                              void* d_out, int out_size, void* d_ws, size_t ws_size,
                              hipStream_t stream) {
    const float* points      = (const float*)d_in[0];
    const float* sigmas      = (const float*)d_in[1];
    const float* exponents   = (const float*)d_in[2];
    const float* intensities = (const float*)d_in[3];
    const float* cam_s       = (const float*)d_in[4];
    const float* cam_e       = (const float*)d_in[5];
    const float* cam_i       = (const float*)d_in[6];

    float* out   = (float*)d_out;
    float* masks = out;                       // 6*256*256 = 393216 floats
    float* blobs = out + NB3 * SZ * SZ;       // 6*128*256*256 floats

    hipLaunchKernelGGL(render_kernel, dim3(MASK_BLOCKS + BLOB_BLOCKS), dim3(256),
                       0, stream,
                       points, sigmas, exponents, intensities,
                       cam_s, cam_e, cam_i, masks, blobs);
}

// Round 5
// 215.343 us; speedup vs baseline: 1.0420x; 1.0420x over previous
//
#include <hip/hip_runtime.h>

#define SZ   256   // image size
#define NPTS 128   // points per batch
#define NB3  6     // bs * ncam = 2*3

// v_exp_f32 / v_log_f32: base-2 exp and log, single-instruction on gfx950.
#define EXP2F(x) __builtin_amdgcn_exp2f(x)
#define LOG2F(x) __builtin_amdgcn_logf(x)

// Global normalization over all 6 camera values (jnp .mean()/.max() reduce the
// whole (2,3) array, not per-row).
__device__ __forceinline__ float norm6(const float* __restrict__ v, int idx) {
    float a0 = v[0], a1 = v[1], a2 = v[2], a3 = v[3], a4 = v[4], a5 = v[5];
    float mean = (a0 + a1 + a2 + a3 + a4 + a5) * (1.0f / 6.0f);
    float inv = 1.0f / mean;
    float b0 = a0 * inv, b1 = a1 * inv, b2 = a2 * inv;
    float b3 = a3 * inv, b4 = a4 * inv, b5 = a5 * inv;
    float d = fmaxf(fmaxf(fmaxf(fabsf(b0 - 1.f), fabsf(b1 - 1.f)),
                          fmaxf(fabsf(b2 - 1.f), fabsf(b3 - 1.f))),
                    fmaxf(fabsf(b4 - 1.f), fabsf(b5 - 1.f)));
    float sf = 0.2f / d;                 // d==0 -> inf -> takes 'vi' branch
    float vi = v[idx] * inv;
    return (sf < 1.0f) ? (vi - 1.0f) * sf + 1.0f : vi;
}

// blob = exp(-(dst*q)^e) = exp2(-exp2(e*log2(dst) + c2)),
//   c2 = e*log2(q) + log2(log2(e))
__global__ __launch_bounds__(256) void render_kernel(
    const float* __restrict__ points,       // (2,3,128,2)
    const float* __restrict__ sigmas,       // (2,128)
    const float* __restrict__ exponents,    // (2,128)
    const float* __restrict__ intensities,  // (2,128)
    const float* __restrict__ cam_s,        // (2,3)
    const float* __restrict__ cam_e,        // (2,3)
    const float* __restrict__ cam_i,        // (2,3)
    float* __restrict__ masks,              // (6,256,256)
    float* __restrict__ blobs)              // (6,128,256,256)
{
    __shared__ float4 s_p[NPTS];   // px, py, e, c2
    __shared__ float  s_i[NPTS];   // intensity

    const int b3  = blockIdx.x >> 8;   // [0,6)
    const int y   = blockIdx.x & 255;  // row
    const int tid = threadIdx.x;       // x pixel

    if (tid < NPTS) {
        const int b = b3 / 3;
        const float cs = norm6(cam_s, b3);
        const float ce = norm6(cam_e, b3);
        const float ci = norm6(cam_i, b3);
        float px = points[(b3 * NPTS + tid) * 2 + 0];
        float py = points[(b3 * NPTS + tid) * 2 + 1];
        px = fminf(fmaxf((px - 128.0f) * (1.0f / 128.0f), -1.0f), 1.0f);
        py = fminf(fmaxf((py - 128.0f) * (1.0f / 128.0f), -1.0f), 1.0f);
        const float sg = sigmas[b * NPTS + tid] * cs;
        const float e  = exponents[b * NPTS + tid] * ce;
        const float q  = 1.0f / (2.0f * sg * sg);
        const float C  = 0.5287663729448977f;           // log2(log2(e))
        const float c2 = fmaf(e, LOG2F(q), C);
        s_p[tid] = make_float4(px, py, e, c2);
        s_i[tid] = intensities[b * NPTS + tid] * ci;
    }
    __syncthreads();

    const float gy = -1.0f + (float)y   * (2.0f / 255.0f);
    const float gx = -1.0f + (float)tid * (2.0f / 255.0f);

    float m = 0.0f;
    float* bptr = blobs + (size_t)b3 * NPTS * SZ * SZ + (size_t)y * SZ + tid;

    #pragma unroll 4
    for (int n = 0; n < NPTS; ++n) {
        const float4 p = s_p[n];
        const float dx = gx - p.x;
        const float dy = gy - p.y;
        const float u  = fmaf(dx, dx, dy * dy);          // squared distance
        // l = e*log2(u) + c2 ; t = 2^l ; blob = 2^(-t)
        const float l  = fmaf(p.z, LOG2F(u), p.w);
        const float t  = EXP2F(l);
        const float bl = EXP2F(-t);                      // u==0 -> t=0 -> bl=1
        // Nontemporal: bypass L2/L3 write-allocate (poisoned-dirty hierarchy)
        __builtin_nontemporal_store(bl, bptr + (size_t)n * (SZ * SZ));
        m = fmaxf(m, bl * s_i[n]);
    }

    __builtin_nontemporal_store(
        fminf(m, 1.0f),
        masks + (size_t)b3 * SZ * SZ + (size_t)y * SZ + tid);
}

extern "C" void kernel_launch(void* const* d_in, const int* in_sizes, int n_in,
                              void* d_out, int out_size, void* d_ws, size_t ws_size,
                              hipStream_t stream) {
    const float* points      = (const float*)d_in[0];
    const float* sigmas      = (const float*)d_in[1];
    const float* exponents   = (const float*)d_in[2];
    const float* intensities = (const float*)d_in[3];
    const float* cam_s       = (const float*)d_in[4];
    const float* cam_e       = (const float*)d_in[5];
    const float* cam_i       = (const float*)d_in[6];

    float* out   = (float*)d_out;
    float* masks = out;                       // 6*256*256 = 393216 floats
    float* blobs = out + NB3 * SZ * SZ;       // 6*128*256*256 floats

    hipLaunchKernelGGL(render_kernel, dim3(NB3 * SZ), dim3(256), 0, stream,
                       points, sigmas, exponents, intensities,
                       cam_s, cam_e, cam_i, masks, blobs);
}

// Round 6
// 208.350 us; speedup vs baseline: 1.0770x; 1.0336x over previous
//
#include <hip/hip_runtime.h>

#define SZ   256   // image size
#define NPTS 128   // points per batch
#define NB3  6     // bs * ncam = 2*3

// v_exp_f32 / v_log_f32: base-2 exp and log, single-instruction on gfx950.
#define EXP2F(x) __builtin_amdgcn_exp2f(x)
#define LOG2F(x) __builtin_amdgcn_logf(x)

// Global normalization over all 6 camera values (jnp .mean()/.max() reduce the
// whole (2,3) array, not per-row).
__device__ __forceinline__ float norm6(const float* __restrict__ v, int idx) {
    float a0 = v[0], a1 = v[1], a2 = v[2], a3 = v[3], a4 = v[4], a5 = v[5];
    float mean = (a0 + a1 + a2 + a3 + a4 + a5) * (1.0f / 6.0f);
    float inv = 1.0f / mean;
    float b0 = a0 * inv, b1 = a1 * inv, b2 = a2 * inv;
    float b3 = a3 * inv, b4 = a4 * inv, b5 = a5 * inv;
    float d = fmaxf(fmaxf(fmaxf(fabsf(b0 - 1.f), fabsf(b1 - 1.f)),
                          fmaxf(fabsf(b2 - 1.f), fabsf(b3 - 1.f))),
                    fmaxf(fabsf(b4 - 1.f), fabsf(b5 - 1.f)));
    float sf = 0.2f / d;                 // d==0 -> inf -> takes 'vi' branch
    float vi = v[idx] * inv;
    return (sf < 1.0f) ? (vi - 1.0f) * sf + 1.0f : vi;
}

// blob = exp(-(dst*q)^e) = exp2(-exp2(e*log2(dst) + c2)),
//   c2 = e*log2(q) + log2(log2(e))
// Early-out: bl < 5e-3  <=>  u > umax = 2^(2.4055/e)/q   (store exact 0)
__global__ __launch_bounds__(256) void render_kernel(
    const float* __restrict__ points,       // (2,3,128,2)
    const float* __restrict__ sigmas,       // (2,128)
    const float* __restrict__ exponents,    // (2,128)
    const float* __restrict__ intensities,  // (2,128)
    const float* __restrict__ cam_s,        // (2,3)
    const float* __restrict__ cam_e,        // (2,3)
    const float* __restrict__ cam_i,        // (2,3)
    float* __restrict__ masks,              // (6,256,256)
    float* __restrict__ blobs)              // (6,128,256,256)
{
    __shared__ float4 s_a[NPTS];   // px, py, umax, intensity  (far path: only read)
    __shared__ float2 s_b[NPTS];   // e, c2                    (near path only)

    const int b3  = blockIdx.x >> 8;   // [0,6)
    const int y   = blockIdx.x & 255;  // row
    const int tid = threadIdx.x;       // x pixel

    if (tid < NPTS) {
        const int b = b3 / 3;
        const float cs = norm6(cam_s, b3);
        const float ce = norm6(cam_e, b3);
        const float ci = norm6(cam_i, b3);
        float px = points[(b3 * NPTS + tid) * 2 + 0];
        float py = points[(b3 * NPTS + tid) * 2 + 1];
        px = fminf(fmaxf((px - 128.0f) * (1.0f / 128.0f), -1.0f), 1.0f);
        py = fminf(fmaxf((py - 128.0f) * (1.0f / 128.0f), -1.0f), 1.0f);
        const float sg = sigmas[b * NPTS + tid] * cs;
        const float e  = exponents[b * NPTS + tid] * ce;
        const float q  = 1.0f / (2.0f * sg * sg);
        const float C  = 0.5287663729448977f;           // log2(log2(e))
        const float lq = LOG2F(q);
        const float c2 = fmaf(e, lq, C);
        // bl >= 5e-3 requires l <= 2.9343 -> e*log2(u*q) <= 2.9343-C
        const float umax = EXP2F(2.4055f / e - lq);
        s_a[tid] = make_float4(px, py, umax, intensities[b * NPTS + tid] * ci);
        s_b[tid] = make_float2(e, c2);
    }
    __syncthreads();

    const float gy = -1.0f + (float)y   * (2.0f / 255.0f);
    const float gx = -1.0f + (float)tid * (2.0f / 255.0f);

    float m = 0.0f;
    float* bptr = blobs + (size_t)b3 * NPTS * SZ * SZ + (size_t)y * SZ + tid;

    for (int n = 0; n < NPTS; ++n) {
        const float4 a = s_a[n];
        const float dx = gx - a.x;
        const float dy = gy - a.y;
        const float u  = fmaf(dx, dx, dy * dy);          // squared distance
        float bl = 0.0f;
        if (u < a.z) {                                   // near region only (~3%)
            const float2 bb = s_b[n];
            // l = e*log2(u) + c2 ; t = 2^l ; blob = 2^(-t)
            const float t = EXP2F(fmaf(bb.x, LOG2F(u), bb.y));
            bl = EXP2F(-t);                              // u==0 -> t=0 -> bl=1
            m = fmaxf(m, bl * a.w);
        }
        bptr[(size_t)n * (SZ * SZ)] = bl;
    }

    masks[(size_t)b3 * SZ * SZ + (size_t)y * SZ + tid] = fminf(m, 1.0f);
}

extern "C" void kernel_launch(void* const* d_in, const int* in_sizes, int n_in,
                              void* d_out, int out_size, void* d_ws, size_t ws_size,
                              hipStream_t stream) {
    const float* points      = (const float*)d_in[0];
    const float* sigmas      = (const float*)d_in[1];
    const float* exponents   = (const float*)d_in[2];
    const float* intensities = (const float*)d_in[3];
    const float* cam_s       = (const float*)d_in[4];
    const float* cam_e       = (const float*)d_in[5];
    const float* cam_i       = (const float*)d_in[6];

    float* out   = (float*)d_out;
    float* masks = out;                       // 6*256*256 = 393216 floats
    float* blobs = out + NB3 * SZ * SZ;       // 6*128*256*256 floats

    hipLaunchKernelGGL(render_kernel, dim3(NB3 * SZ), dim3(256), 0, stream,
                       points, sigmas, exponents, intensities,
                       cam_s, cam_e, cam_i, masks, blobs);
}